// Round 7
// baseline (2666.668 us; speedup 1.0000x reference)
//
#include <hip/hip_runtime.h>

// QuantLinearW4A4Tl: M=8192, K=4096, N=4096, R=32
#define M_ 8192
#define K_ 4096
#define N_ 4096
#define R_ 32
#define KP_ (K_ / 2)

// GEMM: 256x256 block, BK=64 i8, 8 waves (2Mx4N) of 128x64, mfma 32x32x32.
// 2-deep LDS (64 KiB) -> 2 blocks/CU. XCD-clustered block mapping: each XCD
// gets an 8mt x 8nt rectangle -> per-XCD unique operands 16 MB (L2-friendly),
// vs previous mapping streaming all of A per XCD (FETCH 450 MB).
#define BM 256
#define BN 256
#define BK 64
#define NT 64
#define ATILE 16384                    // 256 rows x 64 B (A or B tile)
#define BUF_SZ (2 * ATILE)             // 32 KiB per pipeline stage
#define GRID ((M_ / BM) * (N_ / BN))   // 32 x 16 = 512

typedef __attribute__((ext_vector_type(4)))  int    i32x4;
typedef __attribute__((ext_vector_type(16))) int    i32x16;
typedef __attribute__((ext_vector_type(4)))  float  f32x4;
typedef __attribute__((ext_vector_type(16))) float  f32x16;
typedef __attribute__((ext_vector_type(8)))  __bf16 bf16x8;

__device__ __forceinline__ void gload16(const void* g, void* l) {
  __builtin_amdgcn_global_load_lds(
      (const __attribute__((address_space(1))) unsigned int*)g,
      (__attribute__((address_space(3))) unsigned int*)l, 16, 0, 0);
}

__device__ __forceinline__ unsigned nib2(int b) {
  unsigned lo = (unsigned)(((b & 15) ^ 8) - 8) & 0xFFu;
  unsigned hi = (unsigned)((((b >> 4) & 15) ^ 8) - 8) & 0xFFu;
  return lo | (hi << 8);
}

// ---- tiled repack (A and B share it): image [rt][kt(64)][u(16)][lane(64)][16B]
// granule-lane: row = rt*256 + (u>>1)*32 + (l&31); k8 = kt*64 + (u&1)*32 + (l>>5)*16
__global__ void repack_tiles(const int* __restrict__ in, uint4* __restrict__ out) {
  int i = blockIdx.x * 256 + threadIdx.x;
  int l = i & 63;
  int u = (i >> 6) & 15;
  int tile = i >> 10;                          // rt*64 + kt
  int row = (tile >> 6) * 256 + (u >> 1) * 32 + (l & 31);
  int w0  = (tile & 63) * 32 + (u & 1) * 16 + (l >> 5) * 8;
  const int4* p = (const int4*)(in + (size_t)row * KP_ + w0);
  int4 a = p[0], b = p[1];
  uint4 o;
  o.x = nib2(a.x) | (nib2(a.y) << 16);
  o.y = nib2(a.z) | (nib2(a.w) << 16);
  o.z = nib2(b.x) | (nib2(b.y) << 16);
  o.w = nib2(b.z) | (nib2(b.w) << 16);
  out[i] = o;
}

// ---- f32 -> bf16 (RNE) ----
__device__ __forceinline__ unsigned short f2b(float x) {
  unsigned u = __float_as_uint(x);
  return (unsigned short)((u + 0x7FFFu + ((u >> 16) & 1u)) >> 16);
}

__global__ void f2bf4(const float* __restrict__ in, unsigned short* __restrict__ out, int n4) {
  int stride = gridDim.x * blockDim.x;
  for (int i = blockIdx.x * blockDim.x + threadIdx.x; i < n4; i += stride) {
    float4 f = ((const float4*)in)[i];
    ushort4 o;
    o.x = f2b(f.x); o.y = f2b(f.y); o.z = f2b(f.z); o.w = f2b(f.w);
    ((ushort4*)out)[i] = o;
  }
}

// ---- main GEMM ----
__global__ __launch_bounds__(512, 4) void gemm_w4a4(
    const char* __restrict__ x8t, const char* __restrict__ w8t,
    const unsigned short* __restrict__ xrb, const unsigned short* __restrict__ wob,
    const float* __restrict__ xscale, const float* __restrict__ wscale,
    const float* __restrict__ bias, float* __restrict__ out)
{
  __shared__ __align__(16) char lds[2 * BUF_SZ];   // 64 KiB -> 2 blocks/CU

  const int t  = threadIdx.x;
  const int w  = t >> 6;           // wave 0..7
  const int l  = t & 63;
  const int lr = l & 31;
  const int lh = l >> 5;
  const int wr = w >> 2;           // 0..1 -> 128-row half
  const int wc = w & 3;            // 0..3 -> 64-col quarter

  // XCD-clustered mapping: xcd = bid&7 (round-robin dispatch), each XCD owns
  // an 8mt x 8nt rectangle; all 64 of its blocks are co-resident (2/CU).
  const int xcd = blockIdx.x & 7;
  const int c   = blockIdx.x >> 3;            // 0..63
  const int mt  = (xcd & 3) * 8 + (c & 7);
  const int nt  = (xcd >> 2) * 8 + (c >> 3);
  const int m0  = mt * BM, n0 = nt * BN;

  const char* aT = x8t + (size_t)mt * NT * ATILE;
  const char* bT = w8t + (size_t)nt * NT * ATILE;

  // wave w stages granules {w, w+8} of A and of B (4 gload16/wave/tile)
#define STAGE(tile, buf)                                                      \
  { const char* sa = aT + (size_t)(tile) * ATILE + (w << 10) + (l << 4);      \
    char* da = lds + (buf) * BUF_SZ + (w << 10);                              \
    gload16(sa, da); gload16(sa + 8192, da + 8192);                           \
    const char* sb = bT + (size_t)(tile) * ATILE + (w << 10) + (l << 4);      \
    char* db = lds + (buf) * BUF_SZ + ATILE + (w << 10);                      \
    gload16(sb, db); gload16(sb + 8192, db + 8192); }
#define FENCE asm volatile("" ::: "memory")

  i32x16 acc[4][2] = {};

  // prologue
  STAGE(0, 0)
  asm volatile("s_waitcnt vmcnt(0)" ::: "memory");
  __builtin_amdgcn_s_barrier();
  FENCE;

  for (int kt = 0; kt < NT; ++kt) {
    const char* Ab = lds + (kt & 1) * BUF_SZ;
    const char* Bb = Ab + ATILE;

    // read all fragments of tile kt into regs
    i32x4 af[4][2], bf[2][2];
    #pragma unroll
    for (int mi = 0; mi < 4; ++mi)
      #pragma unroll
      for (int ks = 0; ks < 2; ++ks)
        af[mi][ks] = *(const i32x4*)(Ab + (((wr * 4 + mi) * 2 + ks) << 10) + (l << 4));
    #pragma unroll
    for (int ni = 0; ni < 2; ++ni)
      #pragma unroll
      for (int ks = 0; ks < 2; ++ks)
        bf[ni][ks] = *(const i32x4*)(Bb + (((wc * 2 + ni) * 2 + ks) << 10) + (l << 4));
    FENCE;
    __builtin_amdgcn_s_barrier();   // all waves captured tile kt
    FENCE;

    if (kt < NT - 1) STAGE(kt + 1, (kt + 1) & 1)   // overwrites tile kt-1's buf
    FENCE;

    __builtin_amdgcn_s_setprio(1);
    #pragma unroll
    for (int ks = 0; ks < 2; ++ks)
      #pragma unroll
      for (int mi = 0; mi < 4; ++mi)
        #pragma unroll
        for (int ni = 0; ni < 2; ++ni)
          acc[mi][ni] = __builtin_amdgcn_mfma_i32_32x32x32_i8(
              af[mi][ks], bf[ni][ks], acc[mi][ni], 0, 0, 0);
    __builtin_amdgcn_s_setprio(0);
    FENCE;

    if (kt < NT - 1) {
      asm volatile("s_waitcnt vmcnt(0)" ::: "memory");   // tile kt+1 landed
      __builtin_amdgcn_s_barrier();
      FENCE;
    }
  }

  // ---- epilogue: dequant + bias + rank-32 outlier via 32x32x16 bf16 MFMA ----
  bf16x8 br0[2], br1[2];
  float swv[2], bv[2];
  #pragma unroll
  for (int ni = 0; ni < 2; ++ni) {
    int cg = n0 + wc * 64 + ni * 32 + lr;
    const unsigned short* pw = wob + (size_t)cg * R_;
    br0[ni] = *(const bf16x8*)(pw + lh * 8);
    br1[ni] = *(const bf16x8*)(pw + 16 + lh * 8);
    swv[ni] = wscale[cg];
    bv[ni]  = bias[cg];
  }

  #pragma unroll
  for (int mi = 0; mi < 4; ++mi) {
    const int rbase = m0 + wr * 128 + mi * 32;
    f32x4 sxg[4];
    #pragma unroll
    for (int g = 0; g < 4; ++g)
      sxg[g] = *(const f32x4*)(xscale + rbase + g * 8 + 4 * lh);
    const unsigned short* px = xrb + (size_t)(rbase + lr) * R_;
    bf16x8 ar0 = *(const bf16x8*)(px + lh * 8);
    bf16x8 ar1 = *(const bf16x8*)(px + 16 + lh * 8);

    #pragma unroll
    for (int ni = 0; ni < 2; ++ni) {
      f32x16 cc = {};
      cc = __builtin_amdgcn_mfma_f32_32x32x16_bf16(ar0, br0[ni], cc, 0, 0, 0);
      cc = __builtin_amdgcn_mfma_f32_32x32x16_bf16(ar1, br1[ni], cc, 0, 0, 0);
      const int cg = n0 + wc * 64 + ni * 32 + lr;
      #pragma unroll
      for (int r = 0; r < 16; ++r) {
        int row = rbase + (r & 3) + 8 * (r >> 2) + 4 * lh;
        float v = (float)acc[mi][ni][r] * sxg[r >> 2][r & 3] * swv[ni] + cc[r] + bv[ni];
        __builtin_nontemporal_store(v, &out[(size_t)row * N_ + cg]);
      }
    }
  }
}

extern "C" void kernel_launch(void* const* d_in, const int* in_sizes, int n_in,
                              void* d_out, int out_size, void* d_ws, size_t ws_size,
                              hipStream_t stream) {
  const int*   x_quant   = (const int*)d_in[0];
  const float* x_scale   = (const float*)d_in[1];
  const int*   weight    = (const int*)d_in[2];
  const float* w_scales  = (const float*)d_in[3];
  const float* bias      = (const float*)d_in[4];
  const float* x_r       = (const float*)d_in[5];
  const float* w_outlier = (const float*)d_in[6];
  float* out = (float*)d_out;

  char* ws = (char*)d_ws;
  char*           x8t = ws;                                       // 32 MiB tiled
  char*           w8t = ws + (size_t)M_ * K_;                     // 16 MiB tiled
  unsigned short* xrb = (unsigned short*)(ws + (size_t)M_ * K_ + (size_t)N_ * K_);
  unsigned short* wob = xrb + (size_t)M_ * R_;

  repack_tiles<<<(M_ * K_ / 16) / 256, 256, 0, stream>>>(x_quant, (uint4*)x8t);
  repack_tiles<<<(N_ * K_ / 16) / 256, 256, 0, stream>>>(weight,  (uint4*)w8t);
  f2bf4<<<256, 256, 0, stream>>>(x_r, xrb, M_ * R_ / 4);
  f2bf4<<<128, 256, 0, stream>>>(w_outlier, wob, N_ * R_ / 4);

  gemm_w4a4<<<GRID, 512, 0, stream>>>(
      x8t, w8t, xrb, wob, x_scale, w_scales, bias, out);
}

// Round 8
// 195.461 us; speedup vs baseline: 13.6430x; 13.6430x over previous
//
#include <hip/hip_runtime.h>

// QuantLinearW4A4Tl: M=8192, K=4096, N=4096, R=32
#define M_ 8192
#define K_ 4096
#define N_ 4096
#define R_ 32
#define KP_ (K_ / 2)

// GEMM: 128x128 block, BK=128 i8, 4 waves (2x2) of 64x64, mfma 32x32x32.
// R1's proven 2-barrier schedule (best measured: 44% MfmaUtil) + granule
// image (no VALU addressing, no LDS conflicts) + ~3 blocks/CU stagger +
// XCD 16x16 rectangle mapping (per-XCD operands 16 MB, K-slice L2-resident).
#define BK 128
#define NKT 32                         // K_/BK
#define CHUNK 16384                    // granule image: 256 rows x 64 k-bytes
#define GRID ((M_ / 128) * (N_ / 128)) // 64*32 = 2048

typedef __attribute__((ext_vector_type(4)))  int    i32x4;
typedef __attribute__((ext_vector_type(16))) int    i32x16;
typedef __attribute__((ext_vector_type(4)))  float  f32x4;
typedef __attribute__((ext_vector_type(16))) float  f32x16;
typedef __attribute__((ext_vector_type(8)))  __bf16 bf16x8;

__device__ __forceinline__ void gload16(const void* g, void* l) {
  __builtin_amdgcn_global_load_lds(
      (const __attribute__((address_space(1))) unsigned int*)g,
      (__attribute__((address_space(3))) unsigned int*)l, 16, 0, 0);
}

__device__ __forceinline__ unsigned nib2(int b) {
  unsigned lo = (unsigned)(((b & 15) ^ 8) - 8) & 0xFFu;
  unsigned hi = (unsigned)((((b >> 4) & 15) ^ 8) - 8) & 0xFFu;
  return lo | (hi << 8);
}

// ---- tiled repack (A and B share it): image [rt][ktc(64)][u(16)][lane(64)][16B]
// granule-lane: row = rt*256 + (u>>1)*32 + (l&31); k8 = ktc*64 + (u&1)*32 + (l>>5)*16
__global__ void repack_tiles(const int* __restrict__ in, uint4* __restrict__ out) {
  int i = blockIdx.x * 256 + threadIdx.x;
  int l = i & 63;
  int u = (i >> 6) & 15;
  int tile = i >> 10;                          // rt*64 + ktc
  int row = (tile >> 6) * 256 + (u >> 1) * 32 + (l & 31);
  int w0  = (tile & 63) * 32 + (u & 1) * 16 + (l >> 5) * 8;
  const int4* p = (const int4*)(in + (size_t)row * KP_ + w0);
  int4 a = p[0], b = p[1];
  uint4 o;
  o.x = nib2(a.x) | (nib2(a.y) << 16);
  o.y = nib2(a.z) | (nib2(a.w) << 16);
  o.z = nib2(b.x) | (nib2(b.y) << 16);
  o.w = nib2(b.z) | (nib2(b.w) << 16);
  out[i] = o;
}

// ---- f32 -> bf16 (RNE) ----
__device__ __forceinline__ unsigned short f2b(float x) {
  unsigned u = __float_as_uint(x);
  return (unsigned short)((u + 0x7FFFu + ((u >> 16) & 1u)) >> 16);
}

__global__ void f2bf4(const float* __restrict__ in, unsigned short* __restrict__ out, int n4) {
  int stride = gridDim.x * blockDim.x;
  for (int i = blockIdx.x * blockDim.x + threadIdx.x; i < n4; i += stride) {
    float4 f = ((const float4*)in)[i];
    ushort4 o;
    o.x = f2b(f.x); o.y = f2b(f.y); o.z = f2b(f.z); o.w = f2b(f.w);
    ((ushort4*)out)[i] = o;
  }
}

// ---- main GEMM ----
__global__ __launch_bounds__(256, 3) void gemm_w4a4(
    const char* __restrict__ x8t, const char* __restrict__ w8t,
    const unsigned short* __restrict__ xrb, const unsigned short* __restrict__ wob,
    const float* __restrict__ xscale, const float* __restrict__ wscale,
    const float* __restrict__ bias, float* __restrict__ out)
{
  __shared__ __align__(16) char lds[32768];    // A image 16K + B image 16K

  const int t  = threadIdx.x;
  const int w  = t >> 6;           // wave 0..3
  const int l  = t & 63;
  const int lr = l & 31;
  const int lh = l >> 5;
  const int wr = w >> 1;           // 0..1 -> 64-row half
  const int wc = w & 1;            // 0..1 -> 64-col half

  // XCD rectangle mapping: bid&7 -> XCD (round-robin dispatch); each XCD owns
  // a 16mt x 16nt rectangle of 128x128 tiles (256 blocks, 2 per CU wave-wise).
  const int xcd = blockIdx.x & 7;
  const int c   = blockIdx.x >> 3;             // 0..255
  const int mt  = (xcd & 3) * 16 + (c & 15);   // 0..63
  const int nt  = (xcd >> 2) * 16 + (c >> 4);  // 0..31
  const int m0  = mt * 128, n0 = nt * 128;

  const char* aT = x8t + (size_t)(mt >> 1) * 64 * CHUNK;  // 256-row tile base
  const char* bT = w8t + (size_t)(nt >> 1) * 64 * CHUNK;
  const int ha = (mt & 1) * 8192;              // which 128-row half of the chunk
  const int hb = (nt & 1) * 8192;

  char* ldsA = lds;
  char* ldsB = lds + 16384;

  // BK=128 image for step ktl = halves of chunks c0=2ktl (q=0) and c0+1 (q=1).
  // Wave w: q = w>>1, 4KB piece (w&1). 8 gload16/wave, all identity copies.
#define STAGE(ktl)                                                            \
  { int q = w >> 1, po = (w & 1) * 4096;                                      \
    const char* sa = aT + (size_t)(2 * (ktl) + q) * CHUNK + ha + po + (l << 4); \
    char* da = ldsA + q * 8192 + po;                                          \
    gload16(sa, da);                gload16(sa + 1024, da + 1024);            \
    gload16(sa + 2048, da + 2048);  gload16(sa + 3072, da + 3072);            \
    const char* sb = bT + (size_t)(2 * (ktl) + q) * CHUNK + hb + po + (l << 4); \
    char* db = ldsB + q * 8192 + po;                                          \
    gload16(sb, db);                gload16(sb + 1024, db + 1024);            \
    gload16(sb + 2048, db + 2048);  gload16(sb + 3072, db + 3072); }

  i32x16 acc[2][2] = {};

  for (int ktl = 0; ktl < NKT; ++ktl) {
    __syncthreads();               // all waves done reading previous image
    STAGE(ktl)
    __syncthreads();               // vmcnt(0) drained by compiler -> ready

    // LDS layout: [q][fl(4)][kh] granules of 1KB; frag (fl, ks): q=ks>>1, kh=ks&1
    #pragma unroll
    for (int ks = 0; ks < 4; ++ks) {
      const int ko = (ks >> 1) * 8192 + (ks & 1) * 1024;
      i32x4 a0 = *(const i32x4*)(ldsA + ko + (wr * 2 + 0) * 2048 + (l << 4));
      i32x4 a1 = *(const i32x4*)(ldsA + ko + (wr * 2 + 1) * 2048 + (l << 4));
      i32x4 b0 = *(const i32x4*)(ldsB + ko + (wc * 2 + 0) * 2048 + (l << 4));
      i32x4 b1 = *(const i32x4*)(ldsB + ko + (wc * 2 + 1) * 2048 + (l << 4));
      acc[0][0] = __builtin_amdgcn_mfma_i32_32x32x32_i8(a0, b0, acc[0][0], 0, 0, 0);
      acc[0][1] = __builtin_amdgcn_mfma_i32_32x32x32_i8(a0, b1, acc[0][1], 0, 0, 0);
      acc[1][0] = __builtin_amdgcn_mfma_i32_32x32x32_i8(a1, b0, acc[1][0], 0, 0, 0);
      acc[1][1] = __builtin_amdgcn_mfma_i32_32x32x32_i8(a1, b1, acc[1][1], 0, 0, 0);
    }
  }

  // ---- epilogue: dequant + bias + rank-32 outlier via 32x32x16 bf16 MFMA ----
  bf16x8 br0[2], br1[2];
  float swv[2], bv[2];
  #pragma unroll
  for (int ni = 0; ni < 2; ++ni) {
    int cg = n0 + wc * 64 + ni * 32 + lr;
    const unsigned short* pw = wob + (size_t)cg * R_;
    br0[ni] = *(const bf16x8*)(pw + lh * 8);
    br1[ni] = *(const bf16x8*)(pw + 16 + lh * 8);
    swv[ni] = wscale[cg];
    bv[ni]  = bias[cg];
  }

  #pragma unroll
  for (int mi = 0; mi < 2; ++mi) {
    const int rbase = m0 + wr * 64 + mi * 32;
    f32x4 sxg[4];
    #pragma unroll
    for (int g = 0; g < 4; ++g)
      sxg[g] = *(const f32x4*)(xscale + rbase + g * 8 + 4 * lh);
    const unsigned short* px = xrb + (size_t)(rbase + lr) * R_;
    bf16x8 ar0 = *(const bf16x8*)(px + lh * 8);
    bf16x8 ar1 = *(const bf16x8*)(px + 16 + lh * 8);

    #pragma unroll
    for (int ni = 0; ni < 2; ++ni) {
      f32x16 cc = {};
      cc = __builtin_amdgcn_mfma_f32_32x32x16_bf16(ar0, br0[ni], cc, 0, 0, 0);
      cc = __builtin_amdgcn_mfma_f32_32x32x16_bf16(ar1, br1[ni], cc, 0, 0, 0);
      const int cg = n0 + wc * 64 + ni * 32 + lr;
      #pragma unroll
      for (int r = 0; r < 16; ++r) {
        int row = rbase + (r & 3) + 8 * (r >> 2) + 4 * lh;   // verified C/D map
        out[(size_t)row * N_ + cg] =
            (float)acc[mi][ni][r] * sxg[r >> 2][r & 3] * swv[ni] + cc[r] + bv[ni];
      }
    }
  }
}

extern "C" void kernel_launch(void* const* d_in, const int* in_sizes, int n_in,
                              void* d_out, int out_size, void* d_ws, size_t ws_size,
                              hipStream_t stream) {
  const int*   x_quant   = (const int*)d_in[0];
  const float* x_scale   = (const float*)d_in[1];
  const int*   weight    = (const int*)d_in[2];
  const float* w_scales  = (const float*)d_in[3];
  const float* bias      = (const float*)d_in[4];
  const float* x_r       = (const float*)d_in[5];
  const float* w_outlier = (const float*)d_in[6];
  float* out = (float*)d_out;

  char* ws = (char*)d_ws;
  char*           x8t = ws;                                       // 32 MiB tiled
  char*           w8t = ws + (size_t)M_ * K_;                     // 16 MiB tiled
  unsigned short* xrb = (unsigned short*)(ws + (size_t)M_ * K_ + (size_t)N_ * K_);
  unsigned short* wob = xrb + (size_t)M_ * R_;

  repack_tiles<<<(M_ * K_ / 16) / 256, 256, 0, stream>>>(x_quant, (uint4*)x8t);
  repack_tiles<<<(N_ * K_ / 16) / 256, 256, 0, stream>>>(weight,  (uint4*)w8t);
  f2bf4<<<256, 256, 0, stream>>>(x_r, xrb, M_ * R_ / 4);
  f2bf4<<<128, 256, 0, stream>>>(w_outlier, wob, N_ * R_ / 4);

  gemm_w4a4<<<GRID, 256, 0, stream>>>(
      x8t, w8t, xrb, wob, x_scale, w_scales, bias, out);
}

// Round 9
// 175.029 us; speedup vs baseline: 15.2356x; 1.1167x over previous
//
#include <hip/hip_runtime.h>

// QuantLinearW4A4Tl: M=8192, K=4096, N=4096, R=32
#define M_ 8192
#define K_ 4096
#define N_ 4096
#define R_ 32
#define KP_ (K_ / 2)

// GEMM: 256x256 block, BK=64 i8, 8 waves (2Mx4N) of 128x64, mfma 32x32x32.
// Faithful m201 8-phase-style schedule: 2 phases/K-tile, 2 barriers/phase,
// per-phase stage interleave, counted vmcnt(4) once per tile (never 0 until
// the tail), 3 tile-buffers (96 KiB) with 2-tile lookahead. Granule image
// provides conflict-free ds_read + identity gload_lds (stands in for T2).
#define NKT 64                          // K_/64
#define CHUNK 16384                     // image chunk: 256 rows x 64 k-bytes
#define BUF 32768                       // A chunk + B chunk per K-tile
#define GRID ((M_ / 256) * (N_ / 256))  // 32 x 16 = 512

typedef __attribute__((ext_vector_type(4)))  int    i32x4;
typedef __attribute__((ext_vector_type(16))) int    i32x16;
typedef __attribute__((ext_vector_type(4)))  float  f32x4;
typedef __attribute__((ext_vector_type(16))) float  f32x16;
typedef __attribute__((ext_vector_type(8)))  __bf16 bf16x8;

__device__ __forceinline__ void gload16(const void* g, void* l) {
  __builtin_amdgcn_global_load_lds(
      (const __attribute__((address_space(1))) unsigned int*)g,
      (__attribute__((address_space(3))) unsigned int*)l, 16, 0, 0);
}

__device__ __forceinline__ unsigned nib2(int b) {
  unsigned lo = (unsigned)(((b & 15) ^ 8) - 8) & 0xFFu;
  unsigned hi = (unsigned)((((b >> 4) & 15) ^ 8) - 8) & 0xFFu;
  return lo | (hi << 8);
}

// ---- tiled repack (A and B share it): image [rt][ktc(64)][u(16)][lane(64)][16B]
// granule (u,l): row = rt*256 + (u>>1)*32 + (l&31); k = ktc*64 + (u&1)*32 + (l>>5)*16
// One granule == one 32x32x32-i8 MFMA fragment (1 KiB, contiguous).
__global__ void repack_tiles(const int* __restrict__ in, uint4* __restrict__ out) {
  int i = blockIdx.x * 256 + threadIdx.x;
  int l = i & 63;
  int u = (i >> 6) & 15;
  int tile = i >> 10;                          // rt*64 + ktc
  int row = (tile >> 6) * 256 + (u >> 1) * 32 + (l & 31);
  int w0  = (tile & 63) * 32 + (u & 1) * 16 + (l >> 5) * 8;
  const int4* p = (const int4*)(in + (size_t)row * KP_ + w0);
  int4 a = p[0], b = p[1];
  uint4 o;
  o.x = nib2(a.x) | (nib2(a.y) << 16);
  o.y = nib2(a.z) | (nib2(a.w) << 16);
  o.z = nib2(b.x) | (nib2(b.y) << 16);
  o.w = nib2(b.z) | (nib2(b.w) << 16);
  out[i] = o;
}

// ---- f32 -> bf16 (RNE) ----
__device__ __forceinline__ unsigned short f2b(float x) {
  unsigned u = __float_as_uint(x);
  return (unsigned short)((u + 0x7FFFu + ((u >> 16) & 1u)) >> 16);
}

__global__ void f2bf4(const float* __restrict__ in, unsigned short* __restrict__ out, int n4) {
  int stride = gridDim.x * blockDim.x;
  for (int i = blockIdx.x * blockDim.x + threadIdx.x; i < n4; i += stride) {
    float4 f = ((const float4*)in)[i];
    ushort4 o;
    o.x = f2b(f.x); o.y = f2b(f.y); o.z = f2b(f.z); o.w = f2b(f.w);
    ((ushort4*)out)[i] = o;
  }
}

// ---- main GEMM ----
__global__ __launch_bounds__(512, 2) void gemm_w4a4(
    const char* __restrict__ x8t, const char* __restrict__ w8t,
    const unsigned short* __restrict__ xrb, const unsigned short* __restrict__ wob,
    const float* __restrict__ xscale, const float* __restrict__ wscale,
    const float* __restrict__ bias, float* __restrict__ out)
{
  __shared__ __align__(16) char lds[3 * BUF];   // 96 KiB: 3 K-tile buffers

  const int t  = threadIdx.x;
  const int w  = t >> 6;           // wave 0..7
  const int l  = t & 63;
  const int lr = l & 31;
  const int lh = l >> 5;
  const int wr = w >> 2;           // 0..1 -> 128-row half
  const int wc = w & 3;            // 0..3 -> 64-col quarter

  // linear mapping (best measured FETCH: R1); m fast, n slow
  const int mt = blockIdx.x & 31;
  const int nt = blockIdx.x >> 5;
  const int m0 = mt * 256, n0 = nt * 256;

  const char* aT = x8t + (size_t)mt * NKT * CHUNK;
  const char* bT = w8t + (size_t)nt * NKT * CHUNK;

  // identity staging: thread covers 16 KiB chunk via 2 x gload16 (t*16, +8192)
#define STAGE_A(KT, B_)                                                       \
  { const char* s = aT + (size_t)(KT) * CHUNK + (t << 4);                     \
    char* d = lds + (B_) * BUF + (t << 4);                                    \
    gload16(s, d); gload16(s + 8192, d + 8192); }
#define STAGE_B(KT, B_)                                                       \
  { const char* s = bT + (size_t)(KT) * CHUNK + (t << 4);                     \
    char* d = lds + (B_) * BUF + 16384 + (t << 4);                            \
    gload16(s, d); gload16(s + 8192, d + 8192); }
#define FENCE asm volatile("" ::: "memory")

  // one phase: ds_read 6 frags (ks-slice) | stage | barrier | MFMA x8 | wait | barrier
#define PHASE(KS, STAGE_STMT, WAIT_STMT)                                      \
  { i32x4 af[4], bv[2];                                                       \
    _Pragma("unroll")                                                         \
    for (int mi = 0; mi < 4; ++mi)                                            \
      af[mi] = *(const i32x4*)(Ab + (((wr * 4 + mi) * 2 + (KS)) << 10) + (l << 4)); \
    _Pragma("unroll")                                                         \
    for (int nj = 0; nj < 2; ++nj)                                            \
      bv[nj] = *(const i32x4*)(Bb + (((wc * 2 + nj) * 2 + (KS)) << 10) + (l << 4)); \
    STAGE_STMT;                                                               \
    FENCE; __builtin_amdgcn_s_barrier(); FENCE;                               \
    __builtin_amdgcn_s_setprio(1);                                            \
    _Pragma("unroll")                                                         \
    for (int mi = 0; mi < 4; ++mi)                                            \
      _Pragma("unroll")                                                       \
      for (int nj = 0; nj < 2; ++nj)                                          \
        acc[mi][nj] = __builtin_amdgcn_mfma_i32_32x32x32_i8(                  \
            af[mi], bv[nj], acc[mi][nj], 0, 0, 0);                            \
    __builtin_amdgcn_s_setprio(0);                                            \
    WAIT_STMT;                                                                \
    FENCE; __builtin_amdgcn_s_barrier(); FENCE; }

  i32x16 acc[4][2] = {};

  // prologue: tiles 0,1 staged (8 loads); wait tile 0 (tile 1's 4 remain)
  STAGE_A(0, 0) STAGE_B(0, 0)
  STAGE_A(1, 1) STAGE_B(1, 1)
  asm volatile("s_waitcnt vmcnt(4)" ::: "memory");
  __builtin_amdgcn_s_barrier();
  FENCE;

  for (int kt = 0; kt < NKT; ++kt) {
    const char* Ab = lds + (kt % 3) * BUF;
    const char* Bb = Ab + 16384;
    const int sb = (kt + 2) % 3;

    // phase 0 (ks=0): stage A(kt+2)
    PHASE(0,
          if (kt < NKT - 2) STAGE_A(kt + 2, sb),
          )
    // phase 1 (ks=1): stage B(kt+2); end-of-tile counted wait
    // steady state: outstanding = (kt+1)'s 4 + (kt+2)'s 4 -> vmcnt(4)
    PHASE(1,
          if (kt < NKT - 2) STAGE_B(kt + 2, sb),
          if (kt < NKT - 2) { asm volatile("s_waitcnt vmcnt(4)" ::: "memory"); }
          else if (kt == NKT - 2) { asm volatile("s_waitcnt vmcnt(0)" ::: "memory"); })
  }

  // ---- epilogue: dequant + bias + rank-32 outlier via 32x32x16 bf16 MFMA ----
  bf16x8 br0[2], br1[2];
  float swv[2], bv2[2];
  #pragma unroll
  for (int ni = 0; ni < 2; ++ni) {
    int cg = n0 + wc * 64 + ni * 32 + lr;
    const unsigned short* pw = wob + (size_t)cg * R_;
    br0[ni] = *(const bf16x8*)(pw + lh * 8);
    br1[ni] = *(const bf16x8*)(pw + 16 + lh * 8);
    swv[ni] = wscale[cg];
    bv2[ni] = bias[cg];
  }

  #pragma unroll
  for (int mi = 0; mi < 4; ++mi) {
    const int rbase = m0 + wr * 128 + mi * 32;
    f32x4 sxg[4];
    #pragma unroll
    for (int g = 0; g < 4; ++g)
      sxg[g] = *(const f32x4*)(xscale + rbase + g * 8 + 4 * lh);
    const unsigned short* px = xrb + (size_t)(rbase + lr) * R_;
    bf16x8 ar0 = *(const bf16x8*)(px + lh * 8);
    bf16x8 ar1 = *(const bf16x8*)(px + 16 + lh * 8);

    #pragma unroll
    for (int ni = 0; ni < 2; ++ni) {
      f32x16 cc = {};
      cc = __builtin_amdgcn_mfma_f32_32x32x16_bf16(ar0, br0[ni], cc, 0, 0, 0);
      cc = __builtin_amdgcn_mfma_f32_32x32x16_bf16(ar1, br1[ni], cc, 0, 0, 0);
      const int cg = n0 + wc * 64 + ni * 32 + lr;
      #pragma unroll
      for (int r = 0; r < 16; ++r) {
        int row = rbase + (r & 3) + 8 * (r >> 2) + 4 * lh;   // verified C/D map
        out[(size_t)row * N_ + cg] =
            (float)acc[mi][ni][r] * sxg[r >> 2][r & 3] * swv[ni] + cc[r] + bv2[ni];
      }
    }
  }
}

extern "C" void kernel_launch(void* const* d_in, const int* in_sizes, int n_in,
                              void* d_out, int out_size, void* d_ws, size_t ws_size,
                              hipStream_t stream) {
  const int*   x_quant   = (const int*)d_in[0];
  const float* x_scale   = (const float*)d_in[1];
  const int*   weight    = (const int*)d_in[2];
  const float* w_scales  = (const float*)d_in[3];
  const float* bias      = (const float*)d_in[4];
  const float* x_r       = (const float*)d_in[5];
  const float* w_outlier = (const float*)d_in[6];
  float* out = (float*)d_out;

  char* ws = (char*)d_ws;
  char*           x8t = ws;                                       // 32 MiB tiled
  char*           w8t = ws + (size_t)M_ * K_;                     // 16 MiB tiled
  unsigned short* xrb = (unsigned short*)(ws + (size_t)M_ * K_ + (size_t)N_ * K_);
  unsigned short* wob = xrb + (size_t)M_ * R_;

  repack_tiles<<<(M_ * K_ / 16) / 256, 256, 0, stream>>>(x_quant, (uint4*)x8t);
  repack_tiles<<<(N_ * K_ / 16) / 256, 256, 0, stream>>>(weight,  (uint4*)w8t);
  f2bf4<<<256, 256, 0, stream>>>(x_r, xrb, M_ * R_ / 4);
  f2bf4<<<128, 256, 0, stream>>>(w_outlier, wob, N_ * R_ / 4);

  gemm_w4a4<<<GRID, 512, 0, stream>>>(
      x8t, w8t, xrb, wob, x_scale, w_scales, bias, out);
}